// Round 4
// baseline (522.224 us; speedup 1.0000x reference)
//
#include <hip/hip_runtime.h>
#include <math.h>
#include <stdint.h>

#define HW 4096
#define NC 256
#define NB 4
#define NT 32    // i-tile chunks = HW/BM (per-tile softmax stats)

#define BM 128
#define BN 128
#define BK 32
#define LDP 40   // fallback kernel LDS pitch

typedef _Float16 f16;
typedef _Float16 half8 __attribute__((ext_vector_type(8)));
typedef float f32x4 __attribute__((ext_vector_type(4)));

// ---------------------------------------------------------------------------
// Prep: split f32 -> (f16 hi, f16 lo), transpose [c][i] -> [i][c], store
// PRE-TILED + PRE-SWIZZLED (chunk ch at ch ^ ((r>>1)&3)).  Tile (b,it,kt) is
// a contiguous 128x32-half block; GEMM reads fragments STRAIGHT FROM L2/L3
// (no LDS staging) -- each fm-group of 4 lanes covers a contiguous 64 B row,
// so every frag load is a perfectly-coalesced 1 KB global_load_dwordx4.
// ---------------------------------------------------------------------------
__global__ __launch_bounds__(256) void split_tile(const float* __restrict__ src,
                                                  f16* __restrict__ dh,
                                                  f16* __restrict__ dl) {
    const int it = blockIdx.x;      // hw/128
    const int kt = blockIdx.y;      // NC/32
    const int b  = blockIdx.z;
    const float* S = src + (size_t)b * NC * HW + (size_t)kt * 32 * HW + it * 128;

    __shared__ float st[32][133];
    const int t = threadIdx.x;

    {
        const int i4 = (t & 31) * 4;
        const int c0 = t >> 5;
#pragma unroll
        for (int p = 0; p < 4; ++p) {
            const int c = c0 + p * 8;
            const float4 v = *(const float4*)&S[(size_t)c * HW + i4];
            st[c][i4] = v.x; st[c][i4 + 1] = v.y;
            st[c][i4 + 2] = v.z; st[c][i4 + 3] = v.w;
        }
    }
    __syncthreads();

    const size_t tile_base = ((size_t)b * 256 + (size_t)it * 8 + kt) * (128 * 32);
#pragma unroll
    for (int p = 0; p < 2; ++p) {
        const int cid = t + p * 256;
        const int r = cid >> 2, ch = cid & 3;
        f16 h8[8], l8[8];
#pragma unroll
        for (int q = 0; q < 8; ++q) {
            const float x = st[ch * 8 + q][r];
            h8[q] = (f16)x;
            l8[q] = (f16)(x - (float)h8[q]);
        }
        const int off = r * 32 + ((ch ^ ((r >> 1) & 3)) << 3);
        *(half8*)&dh[tile_base + off] = *(half8*)&h8[0];
        *(half8*)&dl[tile_base + off] = *(half8*)&l8[0];
    }
}

// ---------------------------------------------------------------------------
// Phase 1: corr tile with NO LDS STAGING.  Operands (33.6 MB, pre-tiled) are
// L2/L3-resident; frag loads go straight global->VGPR, K-loop has ZERO
// barriers, waves free-run (12 waves/CU via launch_bounds(256,3)).
// Fused per-tile-column softmax stats epilogue writes p = exp(x - m_tile)
// (f16 into workspace when use16, else f32 into corr) + (m,s) stats.
// XCD-aware bijective swizzle of (it,jt) for L2 panel locality.
// ---------------------------------------------------------------------------
__global__ __launch_bounds__(256, 3) void gemm_corr_direct(const f16* __restrict__ Ah,
                                                           const f16* __restrict__ Al,
                                                           const f16* __restrict__ Bh,
                                                           const f16* __restrict__ Bl,
                                                           float* __restrict__ corr,
                                                           f16* __restrict__ p16,
                                                           const int use16,
                                                           float* __restrict__ pm,
                                                           float* __restrict__ ps) {
    // bijective XCD swizzle: nwg = 32*32 = 1024, 1024 % 8 == 0
    const int flat = blockIdx.y * 32 + blockIdx.x;
    const int swz  = (flat & 7) * 128 + (flat >> 3);
    const int it = swz & 31;
    const int jt = swz >> 5;
    const int b  = blockIdx.z;
    const int i0 = it * BM;
    const int j0 = jt * BN;
    float* Cp  = corr + (size_t)b * HW * HW;
    f16*   Pp  = p16  + (size_t)b * HW * HW;

    const int t    = threadIdx.x;
    const int lane = t & 63;
    const int wave = t >> 6;
    const int wr   = (wave >> 1) * 64;
    const int wc   = (wave & 1) * 64;
    const int fm   = lane & 15;
    const int ca   = lane >> 4;

    const f16* pAh = Ah + ((size_t)b * 256 + (size_t)it * 8) * 4096;
    const f16* pAl = Al + ((size_t)b * 256 + (size_t)it * 8) * 4096;
    const f16* pBh = Bh + ((size_t)b * 256 + (size_t)jt * 8) * 4096;
    const f16* pBl = Bl + ((size_t)b * 256 + (size_t)jt * 8) * 4096;

    // frag offsets within a tile (halfs); swizzle (row>>1)&3 == (fm>>1)&3
    const int swzk = (fm >> 1) & 3;
    const int cswz = ((ca ^ swzk) << 3);
    int aoff[4], boff[4];
#pragma unroll
    for (int u = 0; u < 4; ++u) aoff[u] = (wr + u * 16 + fm) * 32 + cswz;
#pragma unroll
    for (int v = 0; v < 4; ++v) boff[v] = (wc + v * 16 + fm) * 32 + cswz;

    f32x4 acc[4][4];
#pragma unroll
    for (int u = 0; u < 4; ++u)
#pragma unroll
        for (int v = 0; v < 4; ++v) acc[u][v] = (f32x4)(0.f);

    for (int kt = 0; kt < NC / BK; ++kt) {
        const size_t ko = (size_t)kt * 4096;
        half8 fah[4], fal[4], fbh[4], fbl[4];
#pragma unroll
        for (int u = 0; u < 4; ++u) {
            fah[u] = *(const half8*)&pAh[ko + aoff[u]];
            fal[u] = *(const half8*)&pAl[ko + aoff[u]];
        }
#pragma unroll
        for (int v = 0; v < 4; ++v) {
            fbh[v] = *(const half8*)&pBh[ko + boff[v]];
            fbl[v] = *(const half8*)&pBl[ko + boff[v]];
        }
#pragma unroll
        for (int u = 0; u < 4; ++u)
#pragma unroll
            for (int v = 0; v < 4; ++v) {
                acc[u][v] = __builtin_amdgcn_mfma_f32_16x16x32_f16(fah[u], fbh[v], acc[u][v], 0, 0, 0);
                acc[u][v] = __builtin_amdgcn_mfma_f32_16x16x32_f16(fah[u], fbl[v], acc[u][v], 0, 0, 0);
                acc[u][v] = __builtin_amdgcn_mfma_f32_16x16x32_f16(fal[u], fbh[v], acc[u][v], 0, 0, 0);
            }
    }

    // ------------------------------------------------------------------
    // Fused epilogue: per-tile-column max/sum, write p = exp(x - m_tile).
    // C/D layout: col = lane&15 (fm), row = (lane>>4)*4 + reg.
    // ------------------------------------------------------------------
    __shared__ float wred[256];              // [4 waves][64 cols]

    float mcolv[4];
#pragma unroll
    for (int v = 0; v < 4; ++v) {
        float m16 = -INFINITY;
#pragma unroll
        for (int u = 0; u < 4; ++u)
#pragma unroll
            for (int r = 0; r < 4; ++r) m16 = fmaxf(m16, acc[u][v][r]);
        m16 = fmaxf(m16, __shfl_xor(m16, 16));
        m16 = fmaxf(m16, __shfl_xor(m16, 32));
        if ((lane >> 4) == 0) wred[wave * 64 + v * 16 + fm] = m16;
    }
    __syncthreads();

    const int widx = t >> 6;
    float stat_m = 0.f;
    if (t < BN) stat_m = fmaxf(wred[widx * 64 + (t & 63)],
                               wred[(widx + 2) * 64 + (t & 63)]);
#pragma unroll
    for (int v = 0; v < 4; ++v)
        mcolv[v] = fmaxf(wred[(wave & 1) * 64 + v * 16 + fm],
                         wred[((wave & 1) + 2) * 64 + v * 16 + fm]);
    __syncthreads();

    const int q4 = (lane >> 4) * 4;
#pragma unroll
    for (int v = 0; v < 4; ++v) {
        const int jj = j0 + wc + v * 16 + fm;
        float s16 = 0.f;
        if (use16) {
#pragma unroll
            for (int u = 0; u < 4; ++u)
#pragma unroll
                for (int r = 0; r < 4; ++r) {
                    const int ii = i0 + wr + u * 16 + q4 + r;
                    const f16 ph = (f16)__expf(acc[u][v][r] - mcolv[v]);
                    Pp[(size_t)ii * HW + jj] = ph;
                    s16 += (float)ph;      // sum the ROUNDED p: denominator
                }                          // exactly matches the scale pass
        } else {
#pragma unroll
            for (int u = 0; u < 4; ++u)
#pragma unroll
                for (int r = 0; r < 4; ++r) {
                    const int ii = i0 + wr + u * 16 + q4 + r;
                    const float pv = __expf(acc[u][v][r] - mcolv[v]);
                    Cp[(size_t)ii * HW + jj] = pv;
                    s16 += pv;
                }
        }
        s16 += __shfl_xor(s16, 16);
        s16 += __shfl_xor(s16, 32);
        if ((lane >> 4) == 0) wred[wave * 64 + v * 16 + fm] = s16;
    }
    __syncthreads();

    if (t < BN) {
        const float s = wred[widx * 64 + (t & 63)] + wred[(widx + 2) * 64 + (t & 63)];
        const int sidx = it * (NB * HW) + b * HW + j0 + t;
        pm[sidx] = stat_m;
        ps[sidx] = s;
    }
}

// ---------------------------------------------------------------------------
// Fallback phase 1 (round-1 verified kernel) for small workspace.
// ---------------------------------------------------------------------------
__global__ __launch_bounds__(256) void gemm_corr_mfma_fb(const float* __restrict__ f1,
                                                         const float* __restrict__ f2,
                                                         float* __restrict__ corr,
                                                         float* __restrict__ pm,
                                                         float* __restrict__ ps) {
    const int i0 = blockIdx.x * BM;
    const int j0 = blockIdx.y * BN;
    const int b  = blockIdx.z;
    const float* Ap = f1 + (size_t)b * NC * HW;
    const float* Bp = f2 + (size_t)b * NC * HW;
    float* Cp = corr + (size_t)b * HW * HW;

    __shared__ __align__(16) f16 Ash[BM * LDP];
    __shared__ __align__(16) f16 Asl[BM * LDP];
    __shared__ __align__(16) f16 Bsh[BN * LDP];
    __shared__ __align__(16) f16 Bsl[BN * LDP];

    const int t    = threadIdx.x;
    const int lane = t & 63;
    const int wave = t >> 6;
    const int wr   = (wave >> 1) * 64;
    const int wc   = (wave & 1) * 64;
    const int si  = t & 127;
    const int sc0 = (t >> 7) * 16;
    const int fm = lane & 15;
    const int fq = (lane >> 4) * 8;

    f32x4 acc[4][4];
#pragma unroll
    for (int u = 0; u < 4; ++u)
#pragma unroll
        for (int v = 0; v < 4; ++v) acc[u][v] = (f32x4)(0.f);

    for (int k0 = 0; k0 < NC; k0 += BK) {
        float av[16], bv[16];
#pragma unroll
        for (int q = 0; q < 16; ++q) {
            const size_t roff = (size_t)(k0 + sc0 + q) * HW;
            av[q] = Ap[roff + i0 + si];
            bv[q] = Bp[roff + j0 + si];
        }
        f16 ah[16], al[16], bh[16], bl[16];
#pragma unroll
        for (int q = 0; q < 16; ++q) {
            ah[q] = (f16)av[q];  al[q] = (f16)(av[q] - (float)ah[q]);
            bh[q] = (f16)bv[q];  bl[q] = (f16)(bv[q] - (float)bh[q]);
        }
        __syncthreads();
        const int wbase = si * LDP + sc0;
        *(half8*)&Ash[wbase]     = *(half8*)&ah[0];
        *(half8*)&Ash[wbase + 8] = *(half8*)&ah[8];
        *(half8*)&Asl[wbase]     = *(half8*)&al[0];
        *(half8*)&Asl[wbase + 8] = *(half8*)&al[8];
        *(half8*)&Bsh[wbase]     = *(half8*)&bh[0];
        *(half8*)&Bsh[wbase + 8] = *(half8*)&bh[8];
        *(half8*)&Bsl[wbase]     = *(half8*)&bl[0];
        *(half8*)&Bsl[wbase + 8] = *(half8*)&bl[8];
        __syncthreads();

        half8 fah[4], fal[4], fbh[4], fbl[4];
#pragma unroll
        for (int u = 0; u < 4; ++u) {
            const int ar = (wr + u * 16 + fm) * LDP + fq;
            fah[u] = *(const half8*)&Ash[ar];
            fal[u] = *(const half8*)&Asl[ar];
        }
#pragma unroll
        for (int v = 0; v < 4; ++v) {
            const int br = (wc + v * 16 + fm) * LDP + fq;
            fbh[v] = *(const half8*)&Bsh[br];
            fbl[v] = *(const half8*)&Bsl[br];
        }
#pragma unroll
        for (int u = 0; u < 4; ++u)
#pragma unroll
            for (int v = 0; v < 4; ++v) {
                acc[u][v] = __builtin_amdgcn_mfma_f32_16x16x32_f16(fah[u], fbh[v], acc[u][v], 0, 0, 0);
                acc[u][v] = __builtin_amdgcn_mfma_f32_16x16x32_f16(fah[u], fbl[v], acc[u][v], 0, 0, 0);
                acc[u][v] = __builtin_amdgcn_mfma_f32_16x16x32_f16(fal[u], fbh[v], acc[u][v], 0, 0, 0);
            }
    }

    __syncthreads();
    float* wred = (float*)Ash;

    float mcolv[4];
#pragma unroll
    for (int v = 0; v < 4; ++v) {
        float m16 = -INFINITY;
#pragma unroll
        for (int u = 0; u < 4; ++u)
#pragma unroll
            for (int r = 0; r < 4; ++r) m16 = fmaxf(m16, acc[u][v][r]);
        m16 = fmaxf(m16, __shfl_xor(m16, 16));
        m16 = fmaxf(m16, __shfl_xor(m16, 32));
        if ((lane >> 4) == 0) wred[wave * 64 + v * 16 + fm] = m16;
    }
    __syncthreads();

    const int widx = t >> 6;
    float stat_m = 0.f;
    if (t < BN) stat_m = fmaxf(wred[widx * 64 + (t & 63)],
                               wred[(widx + 2) * 64 + (t & 63)]);
    float mcv[4];
#pragma unroll
    for (int v = 0; v < 4; ++v)
        mcv[v] = fmaxf(wred[(wave & 1) * 64 + v * 16 + fm],
                       wred[((wave & 1) + 2) * 64 + v * 16 + fm]);
    __syncthreads();

    const int q4 = (lane >> 4) * 4;
#pragma unroll
    for (int v = 0; v < 4; ++v) {
        const int jj = j0 + wc + v * 16 + fm;
        float s16 = 0.f;
#pragma unroll
        for (int u = 0; u < 4; ++u) {
#pragma unroll
            for (int r = 0; r < 4; ++r) {
                const int ii = i0 + wr + u * 16 + q4 + r;
                const float p = __expf(acc[u][v][r] - mcv[v]);
                Cp[(size_t)ii * HW + jj] = p;
                s16 += p;
            }
        }
        s16 += __shfl_xor(s16, 16);
        s16 += __shfl_xor(s16, 32);
        if ((lane >> 4) == 0) wred[wave * 64 + v * 16 + fm] = s16;
    }
    __syncthreads();

    if (t < BN) {
        const float s = wred[widx * 64 + (t & 63)] + wred[(widx + 2) * 64 + (t & 63)];
        const int sidx = blockIdx.x * (NB * HW) + b * HW + j0 + t;
        pm[sidx] = stat_m;
        ps[sidx] = s;
    }
}

// ---------------------------------------------------------------------------
// Phase 2: merge NT per-tile stats; alpha[c][b][j] = exp(m_c - m_final)/S.
// ---------------------------------------------------------------------------
__global__ __launch_bounds__(256) void softmax_combine(const float* __restrict__ pm,
                                                       const float* __restrict__ ps,
                                                       float* __restrict__ alpha) {
    const int idx = blockIdx.x * 256 + threadIdx.x;
    float pmv[NT], psv[NT], ec[NT];
    float m = -INFINITY;
#pragma unroll
    for (int c = 0; c < NT; ++c) {
        pmv[c] = pm[c * (NB * HW) + idx];
        psv[c] = ps[c * (NB * HW) + idx];
        m = fmaxf(m, pmv[c]);
    }
    float S = 0.f;
#pragma unroll
    for (int c = 0; c < NT; ++c) {
        ec[c] = __expf(pmv[c] - m);
        S += psv[c] * ec[c];
    }
    const float r = 1.0f / S;
#pragma unroll
    for (int c = 0; c < NT; ++c) alpha[c * (NB * HW) + idx] = ec[c] * r;
}

// ---------------------------------------------------------------------------
// Phase 3 (f16 p): out = (float)p16 * alpha[chunk(i)][b][j].  8 elems/thread.
// ---------------------------------------------------------------------------
__global__ __launch_bounds__(256) void softmax_scale16(const f16* __restrict__ p16,
                                                       const float* __restrict__ alpha,
                                                       float* __restrict__ out) {
    const size_t e0 = ((size_t)blockIdx.x * 256 + threadIdx.x) * 8;
    const int b = (int)(e0 >> 24);                 // HW*HW = 2^24
    const int i = ((int)(e0 >> 12)) & (HW - 1);
    const int j = ((int)e0) & (HW - 1);
    const float* ap = &alpha[(size_t)(i >> 7) * (NB * HW) + b * HW + j];
    const float4 a0 = *(const float4*)ap;
    const float4 a1 = *(const float4*)(ap + 4);
    const half8 pv = *(const half8*)&p16[e0];
    float4 o0, o1;
    o0.x = (float)pv[0] * a0.x;  o0.y = (float)pv[1] * a0.y;
    o0.z = (float)pv[2] * a0.z;  o0.w = (float)pv[3] * a0.w;
    o1.x = (float)pv[4] * a1.x;  o1.y = (float)pv[5] * a1.y;
    o1.z = (float)pv[6] * a1.z;  o1.w = (float)pv[7] * a1.w;
    *(float4*)&out[e0]     = o0;
    *(float4*)&out[e0 + 4] = o1;
}

// ---------------------------------------------------------------------------
// Phase 3 (f32 p, fallback): out = p * alpha, in-place, float4 streaming.
// ---------------------------------------------------------------------------
__global__ __launch_bounds__(256) void softmax_scale(float* __restrict__ corr,
                                                     const float* __restrict__ alpha) {
    const size_t base = ((size_t)blockIdx.x * 256 + threadIdx.x) * 4;
    const int b = (int)(base >> 24);
    const int i = ((int)(base >> 12)) & (HW - 1);
    const int j = ((int)base) & (HW - 1);
    const float4 a = *(const float4*)&alpha[(size_t)(i >> 7) * (NB * HW) + b * HW + j];
    float4 x = *(float4*)&corr[base];
    x.x *= a.x; x.y *= a.y; x.z *= a.z; x.w *= a.w;
    *(float4*)&corr[base] = x;
}

extern "C" void kernel_launch(void* const* d_in, const int* in_sizes, int n_in,
                              void* d_out, int out_size, void* d_ws, size_t ws_size,
                              hipStream_t stream) {
    const float* f1 = (const float*)d_in[0];
    const float* f2 = (const float*)d_in[1];
    float* out = (float*)d_out;

    // Workspace layout: pm/ps/alpha (6.3 MB) | 4 tiled f16 arrays (33.6 MB)
    //                   | p16 (134 MB, optional)
    float* pm = (float*)d_ws;
    float* ps = pm + NT * NB * HW;
    float* alpha = ps + NT * NB * HW;
    f16* tiles = (f16*)(alpha + NT * NB * HW);
    const size_t tile_elems = (size_t)NB * 256 * 4096;   // 4,194,304 halfs
    f16* Ah = tiles;
    f16* Al = Ah + tile_elems;
    f16* Bh = Al + tile_elems;
    f16* Bl = Bh + tile_elems;
    f16* p16 = Bl + tile_elems;

    const size_t stats_b = 3ull * NT * NB * HW * 4;
    const size_t tiles_b = 4ull * tile_elems * 2;
    const size_t p16_b   = (size_t)NB * HW * HW * 2;

    if (ws_size >= stats_b + tiles_b) {
        const int use16 = (ws_size >= stats_b + tiles_b + p16_b) ? 1 : 0;
        split_tile<<<dim3(HW / BM, NC / BK, NB), 256, 0, stream>>>(f1, Ah, Al);
        split_tile<<<dim3(HW / BM, NC / BK, NB), 256, 0, stream>>>(f2, Bh, Bl);
        gemm_corr_direct<<<dim3(HW / BM, HW / BN, NB), 256, 0, stream>>>(
            Ah, Al, Bh, Bl, out, p16, use16, pm, ps);
        softmax_combine<<<NB * HW / 256, 256, 0, stream>>>(pm, ps, alpha);
        if (use16)
            softmax_scale16<<<(NB * (size_t)HW * HW) / (8 * 256), 256, 0, stream>>>(p16, alpha, out);
        else
            softmax_scale<<<(NB * (size_t)HW * HW) / (4 * 256), 256, 0, stream>>>(out, alpha);
    } else {
        gemm_corr_mfma_fb<<<dim3(HW / BM, HW / BN, NB), 256, 0, stream>>>(
            f1, f2, out, pm, ps);
        softmax_combine<<<NB * HW / 256, 256, 0, stream>>>(pm, ps, alpha);
        softmax_scale<<<(NB * (size_t)HW * HW) / (4 * 256), 256, 0, stream>>>(out, alpha);
    }
}

// Round 6
// 469.029 us; speedup vs baseline: 1.1134x; 1.1134x over previous
//
#include <hip/hip_runtime.h>
#include <math.h>
#include <stdint.h>

#define HW 4096
#define NC 256
#define NB 4
#define NT 32    // i-tile chunks = HW/BM (per-tile softmax stats)

#define BM 128
#define BN 128
#define BK 32
#define LDP 40   // fallback kernel LDS pitch
#define PTP 132  // epilogue p-tile LDS pitch (halfs): 264 B -> conflict-light

typedef _Float16 f16;
typedef _Float16 half8 __attribute__((ext_vector_type(8)));
typedef float f32x4 __attribute__((ext_vector_type(4)));

#define GLD16(gp, lp) __builtin_amdgcn_global_load_lds( \
    (const __attribute__((address_space(1))) void*)(gp), \
    (__attribute__((address_space(3))) void*)(lp), 16, 0, 0)

// ---------------------------------------------------------------------------
// Prep (merged A+B): split f32 -> (f16 hi, f16 lo), transpose [c][i]->[i][c],
// store PRE-TILED + PRE-SWIZZLED (chunk ch at ch ^ ((r>>1)&3)) so GEMM
// staging is a linear global_load_lds copy and frag ds_reads are 2-way only.
// ---------------------------------------------------------------------------
__global__ __launch_bounds__(256) void split_tile(const float* __restrict__ f1,
                                                  const float* __restrict__ f2,
                                                  f16* __restrict__ Ah,
                                                  f16* __restrict__ Al,
                                                  f16* __restrict__ Bh,
                                                  f16* __restrict__ Bl) {
    const int it = blockIdx.x;      // hw/128
    const int kt = blockIdx.y;      // NC/32
    const int zz = blockIdx.z;      // 0..7: which source + batch
    const int b  = zz & 3;
    const float* src = (zz < 4) ? f1 : f2;
    f16* dh = (zz < 4) ? Ah : Bh;
    f16* dl = (zz < 4) ? Al : Bl;
    const float* S = src + (size_t)b * NC * HW + (size_t)kt * 32 * HW + it * 128;

    __shared__ float st[32][133];
    const int t = threadIdx.x;

    {
        const int i4 = (t & 31) * 4;
        const int c0 = t >> 5;
#pragma unroll
        for (int p = 0; p < 4; ++p) {
            const int c = c0 + p * 8;
            const float4 v = *(const float4*)&S[(size_t)c * HW + i4];
            st[c][i4] = v.x; st[c][i4 + 1] = v.y;
            st[c][i4 + 2] = v.z; st[c][i4 + 3] = v.w;
        }
    }
    __syncthreads();

    const size_t tile_base = ((size_t)b * 256 + (size_t)it * 8 + kt) * (128 * 32);
#pragma unroll
    for (int p = 0; p < 2; ++p) {
        const int cid = t + p * 256;
        const int r = cid >> 2, ch = cid & 3;
        f16 h8[8], l8[8];
#pragma unroll
        for (int q = 0; q < 8; ++q) {
            const float x = st[ch * 8 + q][r];
            h8[q] = (f16)x;
            l8[q] = (f16)(x - (float)h8[q]);
        }
        const int off = r * 32 + ((ch ^ ((r >> 1) & 3)) << 3);
        *(half8*)&dh[tile_base + off] = *(half8*)&h8[0];
        *(half8*)&dl[tile_base + off] = *(half8*)&l8[0];
    }
}

// ---------------------------------------------------------------------------
// Phase 1: corr tile from pre-tiled f16 operands.  ROUND-3 STRUCTURE
// (verified fastest): T3-minimum 2-phase dbuf pipeline -- prefetch tile kt+1
// via global_load_lds into buf^1 while MFMAs run on buf; ONE barrier per
// K-step, vmcnt drains AFTER the MFMAs.
// Epilogue stages the 128x128 f16 p-tile in LDS (dead dbuf space) and
// copies out in 256B-contiguous rows -- kills the 41% write amplification
// seen in round 4 (WRITE_SIZE 192 MB vs 136 ideal; 32B segments).
// ---------------------------------------------------------------------------
__global__ __launch_bounds__(256) void gemm_corr_mfma_t(const f16* __restrict__ Ah,
                                                        const f16* __restrict__ Al,
                                                        const f16* __restrict__ Bh,
                                                        const f16* __restrict__ Bl,
                                                        float* __restrict__ corr,
                                                        f16* __restrict__ p16,
                                                        const int use16,
                                                        float* __restrict__ pm,
                                                        float* __restrict__ ps) {
    // bijective XCD swizzle: nwg = 32*32 = 1024, 1024 % 8 == 0
    const int flat = blockIdx.y * 32 + blockIdx.x;
    const int swz  = (flat & 7) * 128 + (flat >> 3);
    const int it = swz & 31;
    const int jt = swz >> 5;
    const int b  = blockIdx.z;
    const int i0 = it * BM;
    const int j0 = jt * BN;
    float* Cp  = corr + (size_t)b * HW * HW;
    f16*   Pp  = p16  + (size_t)b * HW * HW;

    // one 64 KB block, manually partitioned (epilogue reuses it as p-tile)
    __shared__ __align__(16) f16 smem[8 * 4096];
    f16* sAh = smem;
    f16* sAl = smem + 8192;
    f16* sBh = smem + 16384;
    f16* sBl = smem + 24576;

    const int t    = threadIdx.x;
    const int lane = t & 63;
    const int wave = t >> 6;
    const int wr   = (wave >> 1) * 64;
    const int wc   = (wave & 1) * 64;
    const int fm   = lane & 15;
    const int ca   = lane >> 4;

    const size_t abase = ((size_t)b * 256 + (size_t)it * 8) * 4096;
    const size_t bbase = ((size_t)b * 256 + (size_t)jt * 8) * 4096;

    const int swzk = (fm >> 1) & 3;
    const int cswz = ((ca ^ swzk) << 3);
    int aoff[4], boff[4];
#pragma unroll
    for (int u = 0; u < 4; ++u) aoff[u] = (wr + u * 16 + fm) * 32 + cswz;
#pragma unroll
    for (int v = 0; v < 4; ++v) boff[v] = (wc + v * 16 + fm) * 32 + cswz;

    f32x4 acc[4][4];
#pragma unroll
    for (int u = 0; u < 4; ++u)
#pragma unroll
        for (int v = 0; v < 4; ++v) acc[u][v] = (f32x4)(0.f);

    const int stg = wave * 1024 + lane * 8;   // per-lane global half offset

#define STAGE(buf, kt_) do {                                             \
        const size_t koff_ = (size_t)(kt_) * 4096;                       \
        _Pragma("unroll")                                                \
        for (int p_ = 0; p_ < 2; ++p_) {                                 \
            const int h_  = stg + p_ * 512;                              \
            const int lb_ = (buf) * 4096 + (wave * 2 + p_) * 512;        \
            GLD16(Ah + abase + koff_ + h_, &sAh[lb_]);                   \
            GLD16(Al + abase + koff_ + h_, &sAl[lb_]);                   \
            GLD16(Bh + bbase + koff_ + h_, &sBh[lb_]);                   \
            GLD16(Bl + bbase + koff_ + h_, &sBl[lb_]);                   \
        }                                                                \
    } while (0)

    STAGE(0, 0);
    __syncthreads();                       // prologue tile resident

#pragma unroll
    for (int kt = 0; kt < NC / BK; ++kt) {
        const int cur = kt & 1;
        if (kt < NC / BK - 1) STAGE(cur ^ 1, kt + 1);   // async prefetch

        const int cb = cur * 4096;
        half8 fah[4], fal[4], fbh[4], fbl[4];
#pragma unroll
        for (int u = 0; u < 4; ++u) {
            fah[u] = *(const half8*)&sAh[cb + aoff[u]];
            fal[u] = *(const half8*)&sAl[cb + aoff[u]];
        }
#pragma unroll
        for (int v = 0; v < 4; ++v) {
            fbh[v] = *(const half8*)&sBh[cb + boff[v]];
            fbl[v] = *(const half8*)&sBl[cb + boff[v]];
        }
#pragma unroll
        for (int u = 0; u < 4; ++u)
#pragma unroll
            for (int v = 0; v < 4; ++v) {
                acc[u][v] = __builtin_amdgcn_mfma_f32_16x16x32_f16(fah[u], fbh[v], acc[u][v], 0, 0, 0);
                acc[u][v] = __builtin_amdgcn_mfma_f32_16x16x32_f16(fah[u], fbl[v], acc[u][v], 0, 0, 0);
                acc[u][v] = __builtin_amdgcn_mfma_f32_16x16x32_f16(fal[u], fbh[v], acc[u][v], 0, 0, 0);
            }
        __syncthreads();   // prefetch complete (vmcnt drains AFTER MFMAs) +
                           // all waves done reading buf cur
    }
#undef STAGE

    // ------------------------------------------------------------------
    // Fused epilogue: per-tile-column max/sum; p = exp(x - m_tile).
    // C/D layout: col = lane&15 (fm), row = (lane>>4)*4 + reg.
    // f16 path stages p in LDS (pt) and copies out coalesced.
    // ------------------------------------------------------------------
    f16*   pt   = smem;                         // [128][PTP] halfs (33.8 KB)
    float* wred = (float*)&smem[24576];         // byte 49152, disjoint from pt

    float mcolv[4];
#pragma unroll
    for (int v = 0; v < 4; ++v) {
        float m16 = -INFINITY;
#pragma unroll
        for (int u = 0; u < 4; ++u)
#pragma unroll
            for (int r = 0; r < 4; ++r) m16 = fmaxf(m16, acc[u][v][r]);
        m16 = fmaxf(m16, __shfl_xor(m16, 16));
        m16 = fmaxf(m16, __shfl_xor(m16, 32));
        if ((lane >> 4) == 0) wred[wave * 64 + v * 16 + fm] = m16;
    }
    __syncthreads();

    const int widx = t >> 6;
    float stat_m = 0.f;
    if (t < BN) stat_m = fmaxf(wred[widx * 64 + (t & 63)],
                               wred[(widx + 2) * 64 + (t & 63)]);
#pragma unroll
    for (int v = 0; v < 4; ++v)
        mcolv[v] = fmaxf(wred[(wave & 1) * 64 + v * 16 + fm],
                         wred[((wave & 1) + 2) * 64 + v * 16 + fm]);
    __syncthreads();                 // mcolv reads done; wred reusable

    const int q4 = (lane >> 4) * 4;
#pragma unroll
    for (int v = 0; v < 4; ++v) {
        const int jj = j0 + wc + v * 16 + fm;
        float s16 = 0.f;
        if (use16) {
            const int cc = wc + v * 16 + fm;       // col within tile
#pragma unroll
            for (int u = 0; u < 4; ++u)
#pragma unroll
                for (int r = 0; r < 4; ++r) {
                    const int rr = wr + u * 16 + q4 + r;
                    const f16 ph = (f16)__expf(acc[u][v][r] - mcolv[v]);
                    pt[rr * PTP + cc] = ph;        // LDS scatter (2-way ok)
                    s16 += (float)ph;  // sum the ROUNDED p: denominator
                }                      // exactly matches the scale pass
        } else {
#pragma unroll
            for (int u = 0; u < 4; ++u)
#pragma unroll
                for (int r = 0; r < 4; ++r) {
                    const int ii = i0 + wr + u * 16 + q4 + r;
                    const float pv = __expf(acc[u][v][r] - mcolv[v]);
                    Cp[(size_t)ii * HW + jj] = pv;
                    s16 += pv;
                }
        }
        s16 += __shfl_xor(s16, 16);
        s16 += __shfl_xor(s16, 32);
        if ((lane >> 4) == 0) wred[wave * 64 + v * 16 + fm] = s16;
    }
    __syncthreads();

    if (use16) {
        // coalesced copy-out: thread t handles row rr = t>>1, 64 cols
        const int rr = t >> 1;
        const int cc = (t & 1) * 64;
        f16* dst = &Pp[(size_t)(i0 + rr) * HW + j0 + cc];
        const f16* srcr = &pt[rr * PTP + cc];
#pragma unroll
        for (int k = 0; k < 8; ++k)
            *(half8*)&dst[k * 8] = *(const half8*)&srcr[k * 8];
    }

    if (t < BN) {
        const float s = wred[widx * 64 + (t & 63)] + wred[(widx + 2) * 64 + (t & 63)];
        const int sidx = it * (NB * HW) + b * HW + j0 + t;
        pm[sidx] = stat_m;
        ps[sidx] = s;
    }
}

// ---------------------------------------------------------------------------
// Fallback phase 1 (round-1 verified kernel) for small workspace.
// ---------------------------------------------------------------------------
__global__ __launch_bounds__(256) void gemm_corr_mfma_fb(const float* __restrict__ f1,
                                                         const float* __restrict__ f2,
                                                         float* __restrict__ corr,
                                                         float* __restrict__ pm,
                                                         float* __restrict__ ps) {
    const int i0 = blockIdx.x * BM;
    const int j0 = blockIdx.y * BN;
    const int b  = blockIdx.z;
    const float* Ap = f1 + (size_t)b * NC * HW;
    const float* Bp = f2 + (size_t)b * NC * HW;
    float* Cp = corr + (size_t)b * HW * HW;

    __shared__ __align__(16) f16 Ash[BM * LDP];
    __shared__ __align__(16) f16 Asl[BM * LDP];
    __shared__ __align__(16) f16 Bsh[BN * LDP];
    __shared__ __align__(16) f16 Bsl[BN * LDP];

    const int t    = threadIdx.x;
    const int lane = t & 63;
    const int wave = t >> 6;
    const int wr   = (wave >> 1) * 64;
    const int wc   = (wave & 1) * 64;
    const int si  = t & 127;
    const int sc0 = (t >> 7) * 16;
    const int fm = lane & 15;
    const int fq = (lane >> 4) * 8;

    f32x4 acc[4][4];
#pragma unroll
    for (int u = 0; u < 4; ++u)
#pragma unroll
        for (int v = 0; v < 4; ++v) acc[u][v] = (f32x4)(0.f);

    for (int k0 = 0; k0 < NC; k0 += BK) {
        float av[16], bv[16];
#pragma unroll
        for (int q = 0; q < 16; ++q) {
            const size_t roff = (size_t)(k0 + sc0 + q) * HW;
            av[q] = Ap[roff + i0 + si];
            bv[q] = Bp[roff + j0 + si];
        }
        f16 ah[16], al[16], bh[16], bl[16];
#pragma unroll
        for (int q = 0; q < 16; ++q) {
            ah[q] = (f16)av[q];  al[q] = (f16)(av[q] - (float)ah[q]);
            bh[q] = (f16)bv[q];  bl[q] = (f16)(bv[q] - (float)bh[q]);
        }
        __syncthreads();
        const int wbase = si * LDP + sc0;
        *(half8*)&Ash[wbase]     = *(half8*)&ah[0];
        *(half8*)&Ash[wbase + 8] = *(half8*)&ah[8];
        *(half8*)&Asl[wbase]     = *(half8*)&al[0];
        *(half8*)&Asl[wbase + 8] = *(half8*)&al[8];
        *(half8*)&Bsh[wbase]     = *(half8*)&bh[0];
        *(half8*)&Bsh[wbase + 8] = *(half8*)&bh[8];
        *(half8*)&Bsl[wbase]     = *(half8*)&bl[0];
        *(half8*)&Bsl[wbase + 8] = *(half8*)&bl[8];
        __syncthreads();

        half8 fah[4], fal[4], fbh[4], fbl[4];
#pragma unroll
        for (int u = 0; u < 4; ++u) {
            const int ar = (wr + u * 16 + fm) * LDP + fq;
            fah[u] = *(const half8*)&Ash[ar];
            fal[u] = *(const half8*)&Asl[ar];
        }
#pragma unroll
        for (int v = 0; v < 4; ++v) {
            const int br = (wc + v * 16 + fm) * LDP + fq;
            fbh[v] = *(const half8*)&Bsh[br];
            fbl[v] = *(const half8*)&Bsl[br];
        }
#pragma unroll
        for (int u = 0; u < 4; ++u)
#pragma unroll
            for (int v = 0; v < 4; ++v) {
                acc[u][v] = __builtin_amdgcn_mfma_f32_16x16x32_f16(fah[u], fbh[v], acc[u][v], 0, 0, 0);
                acc[u][v] = __builtin_amdgcn_mfma_f32_16x16x32_f16(fah[u], fbl[v], acc[u][v], 0, 0, 0);
                acc[u][v] = __builtin_amdgcn_mfma_f32_16x16x32_f16(fal[u], fbh[v], acc[u][v], 0, 0, 0);
            }
    }

    __syncthreads();
    float* wred = (float*)Ash;

    float mcolv[4];
#pragma unroll
    for (int v = 0; v < 4; ++v) {
        float m16 = -INFINITY;
#pragma unroll
        for (int u = 0; u < 4; ++u)
#pragma unroll
            for (int r = 0; r < 4; ++r) m16 = fmaxf(m16, acc[u][v][r]);
        m16 = fmaxf(m16, __shfl_xor(m16, 16));
        m16 = fmaxf(m16, __shfl_xor(m16, 32));
        if ((lane >> 4) == 0) wred[wave * 64 + v * 16 + fm] = m16;
    }
    __syncthreads();

    const int widx = t >> 6;
    float stat_m = 0.f;
    if (t < BN) stat_m = fmaxf(wred[widx * 64 + (t & 63)],
                               wred[(widx + 2) * 64 + (t & 63)]);
    float mcv[4];
#pragma unroll
    for (int v = 0; v < 4; ++v)
        mcv[v] = fmaxf(wred[(wave & 1) * 64 + v * 16 + fm],
                       wred[((wave & 1) + 2) * 64 + v * 16 + fm]);
    __syncthreads();

    const int q4 = (lane >> 4) * 4;
#pragma unroll
    for (int v = 0; v < 4; ++v) {
        const int jj = j0 + wc + v * 16 + fm;
        float s16 = 0.f;
#pragma unroll
        for (int u = 0; u < 4; ++u) {
#pragma unroll
            for (int r = 0; r < 4; ++r) {
                const int ii = i0 + wr + u * 16 + q4 + r;
                const float p = __expf(acc[u][v][r] - mcv[v]);
                Cp[(size_t)ii * HW + jj] = p;
                s16 += p;
            }
        }
        s16 += __shfl_xor(s16, 16);
        s16 += __shfl_xor(s16, 32);
        if ((lane >> 4) == 0) wred[wave * 64 + v * 16 + fm] = s16;
    }
    __syncthreads();

    if (t < BN) {
        const float s = wred[widx * 64 + (t & 63)] + wred[(widx + 2) * 64 + (t & 63)];
        const int sidx = blockIdx.x * (NB * HW) + b * HW + j0 + t;
        pm[sidx] = stat_m;
        ps[sidx] = s;
    }
}

// ---------------------------------------------------------------------------
// Phase 2: merge NT per-tile stats; alpha[c][b][j] = exp(m_c - m_final)/S.
// ---------------------------------------------------------------------------
__global__ __launch_bounds__(256) void softmax_combine(const float* __restrict__ pm,
                                                       const float* __restrict__ ps,
                                                       float* __restrict__ alpha) {
    const int idx = blockIdx.x * 256 + threadIdx.x;
    float pmv[NT], psv[NT], ec[NT];
    float m = -INFINITY;
#pragma unroll
    for (int c = 0; c < NT; ++c) {
        pmv[c] = pm[c * (NB * HW) + idx];
        psv[c] = ps[c * (NB * HW) + idx];
        m = fmaxf(m, pmv[c]);
    }
    float S = 0.f;
#pragma unroll
    for (int c = 0; c < NT; ++c) {
        ec[c] = __expf(pmv[c] - m);
        S += psv[c] * ec[c];
    }
    const float r = 1.0f / S;
#pragma unroll
    for (int c = 0; c < NT; ++c) alpha[c * (NB * HW) + idx] = ec[c] * r;
}

// ---------------------------------------------------------------------------
// Phase 3 (f16 p): out = (float)p16 * alpha[chunk(i)][b][j].  8 elems/thread.
// ---------------------------------------------------------------------------
__global__ __launch_bounds__(256) void softmax_scale16(const f16* __restrict__ p16,
                                                       const float* __restrict__ alpha,
                                                       float* __restrict__ out) {
    const size_t e0 = ((size_t)blockIdx.x * 256 + threadIdx.x) * 8;
    const int b = (int)(e0 >> 24);                 // HW*HW = 2^24
    const int i = ((int)(e0 >> 12)) & (HW - 1);
    const int j = ((int)e0) & (HW - 1);
    const float* ap = &alpha[(size_t)(i >> 7) * (NB * HW) + b * HW + j];
    const float4 a0 = *(const float4*)ap;
    const float4 a1 = *(const float4*)(ap + 4);
    const half8 pv = *(const half8*)&p16[e0];
    float4 o0, o1;
    o0.x = (float)pv[0] * a0.x;  o0.y = (float)pv[1] * a0.y;
    o0.z = (float)pv[2] * a0.z;  o0.w = (float)pv[3] * a0.w;
    o1.x = (float)pv[4] * a1.x;  o1.y = (float)pv[5] * a1.y;
    o1.z = (float)pv[6] * a1.z;  o1.w = (float)pv[7] * a1.w;
    *(float4*)&out[e0]     = o0;
    *(float4*)&out[e0 + 4] = o1;
}

// ---------------------------------------------------------------------------
// Phase 3 (f32 p, fallback): out = p * alpha, in-place, float4 streaming.
// ---------------------------------------------------------------------------
__global__ __launch_bounds__(256) void softmax_scale(float* __restrict__ corr,
                                                     const float* __restrict__ alpha) {
    const size_t base = ((size_t)blockIdx.x * 256 + threadIdx.x) * 4;
    const int b = (int)(base >> 24);
    const int i = ((int)(base >> 12)) & (HW - 1);
    const int j = ((int)base) & (HW - 1);
    const float4 a = *(const float4*)&alpha[(size_t)(i >> 7) * (NB * HW) + b * HW + j];
    float4 x = *(float4*)&corr[base];
    x.x *= a.x; x.y *= a.y; x.z *= a.z; x.w *= a.w;
    *(float4*)&corr[base] = x;
}

extern "C" void kernel_launch(void* const* d_in, const int* in_sizes, int n_in,
                              void* d_out, int out_size, void* d_ws, size_t ws_size,
                              hipStream_t stream) {
    const float* f1 = (const float*)d_in[0];
    const float* f2 = (const float*)d_in[1];
    float* out = (float*)d_out;

    // Workspace layout: pm/ps/alpha (6.3 MB) | 4 tiled f16 arrays (33.6 MB)
    //                   | p16 (134 MB, optional)
    float* pm = (float*)d_ws;
    float* ps = pm + NT * NB * HW;
    float* alpha = ps + NT * NB * HW;
    f16* tiles = (f16*)(alpha + NT * NB * HW);
    const size_t tile_elems = (size_t)NB * 256 * 4096;   // 4,194,304 halfs
    f16* Ah = tiles;
    f16* Al = Ah + tile_elems;
    f16* Bh = Al + tile_elems;
    f16* Bl = Bh + tile_elems;
    f16* p16 = Bl + tile_elems;

    const size_t stats_b = 3ull * NT * NB * HW * 4;
    const size_t tiles_b = 4ull * tile_elems * 2;
    const size_t p16_b   = (size_t)NB * HW * HW * 2;

    if (ws_size >= stats_b + tiles_b) {
        const int use16 = (ws_size >= stats_b + tiles_b + p16_b) ? 1 : 0;
        split_tile<<<dim3(HW / BM, NC / BK, 2 * NB), 256, 0, stream>>>(
            f1, f2, Ah, Al, Bh, Bl);
        gemm_corr_mfma_t<<<dim3(HW / BM, HW / BN, NB), 256, 0, stream>>>(
            Ah, Al, Bh, Bl, out, p16, use16, pm, ps);
        softmax_combine<<<NB * HW / 256, 256, 0, stream>>>(pm, ps, alpha);
        if (use16)
            softmax_scale16<<<(NB * (size_t)HW * HW) / (8 * 256), 256, 0, stream>>>(p16, alpha, out);
        else
            softmax_scale<<<(NB * (size_t)HW * HW) / (4 * 256), 256, 0, stream>>>(out, alpha);
    } else {
        gemm_corr_mfma_fb<<<dim3(HW / BM, HW / BN, NB), 256, 0, stream>>>(
            f1, f2, out, pm, ps);
        softmax_combine<<<NB * HW / 256, 256, 0, stream>>>(pm, ps, alpha);
        softmax_scale<<<(NB * (size_t)HW * HW) / (4 * 256), 256, 0, stream>>>(out, alpha);
    }
}